// Round 1
// baseline (854.598 us; speedup 1.0000x reference)
//
#include <hip/hip_runtime.h>
#include <hip/hip_bf16.h>

// EdgewiseReduce: out[n, :] = sum_{e : dst[e]==n} edge_data[e, :] * 0.5
// E = 1.6M, D = 32, N = 100K. Memory-bound scatter-sum.
//
// Strategy: 8 threads per edge, each loads one float4 (16B coalesced),
// scales by 0.5, and issues 4 hardware fp32 atomics into the output row.
// Output region (12.8 MB) is L2/MALL resident, so atomic RMWs stay on-die.

#define FACTOR 0.5f
#define D 32

__global__ void EdgewiseReduce_64776696758368_kernel(
    const float4* __restrict__ edge_data,   // [E, D/4] as float4
    const int* __restrict__ edge_dst,       // [E]
    float* __restrict__ out,                // [N, D]
    int E, int N) {
  int tid = blockIdx.x * blockDim.x + threadIdx.x;
  int e = tid >> 3;          // edge index
  int q = tid & 7;           // which float4 of the 8 per edge
  if (e >= E) return;

  int dst = edge_dst[e];
  // Defensive bounds check: if index dtype assumption is wrong we produce
  // wrong values (caught by absmax) instead of corrupting memory.
  if (dst < 0 || dst >= N) return;

  float4 v = edge_data[(size_t)e * (D / 4) + q];
  float* p = out + (size_t)dst * D + q * 4;
  unsafeAtomicAdd(p + 0, v.x * FACTOR);
  unsafeAtomicAdd(p + 1, v.y * FACTOR);
  unsafeAtomicAdd(p + 2, v.z * FACTOR);
  unsafeAtomicAdd(p + 3, v.w * FACTOR);
}

extern "C" void kernel_launch(void* const* d_in, const int* in_sizes, int n_in,
                              void* d_out, int out_size, void* d_ws, size_t ws_size,
                              hipStream_t stream) {
  const float4* edge_data = (const float4*)d_in[0];
  const int* edge_dst = (const int*)d_in[1];
  float* out = (float*)d_out;

  int E = in_sizes[1];            // number of edges
  int N = out_size / D;           // number of nodes

  // Output is poisoned 0xAA before every timed launch; zero it first.
  hipMemsetAsync(d_out, 0, (size_t)out_size * sizeof(float), stream);

  int total = E * 8;              // 8 threads per edge
  int block = 256;
  int grid = (total + block - 1) / block;
  EdgewiseReduce_64776696758368_kernel<<<grid, block, 0, stream>>>(
      edge_data, edge_dst, out, E, N);
}

// Round 2
// 494.126 us; speedup vs baseline: 1.7295x; 1.7295x over previous
//
#include <hip/hip_runtime.h>
#include <hip/hip_bf16.h>

// EdgewiseReduce: out[n, :] = sum_{e : dst[e]==n} edge_data[e, :] * 0.5
// E = 1.6M, D = 32, N = 100K.
//
// Round 1 (pure f32 atomic scatter) was atomic-throughput bound:
// 51.2M atomics -> 819 MB of 16B memory-side write transactions, 647 us.
// Round 2: counting-sort the edge ids by dst (3.2M *int* atomics total),
// then a gather-reduce pass that reads each edge row exactly once and
// writes each output row exactly once — zero f32 atomics.

#define D 32
#define FACTOR 0.5f

// ---------- Phase A: count edges per node ----------
__global__ void count_kernel(const int* __restrict__ dst, int* __restrict__ counts,
                             int E, int N) {
  int e = blockIdx.x * blockDim.x + threadIdx.x;
  if (e < E) {
    int d = dst[e];
    if (d >= 0 && d < N) atomicAdd(&counts[d], 1);
  }
}

// ---------- Phase B: exclusive scan (3 kernels, 256/block) ----------
__global__ void scan1_kernel(const int* __restrict__ counts, int* __restrict__ excl,
                             int* __restrict__ blocksums, int N) {
  __shared__ int buf[256];
  int i = blockIdx.x * 256 + threadIdx.x;
  int v = (i < N) ? counts[i] : 0;
  buf[threadIdx.x] = v;
  __syncthreads();
  for (int off = 1; off < 256; off <<= 1) {
    int t = (threadIdx.x >= off) ? buf[threadIdx.x - off] : 0;
    __syncthreads();
    buf[threadIdx.x] += t;
    __syncthreads();
  }
  int incl = buf[threadIdx.x];
  if (i < N) excl[i] = incl - v;              // exclusive within block
  if (threadIdx.x == 255) blocksums[blockIdx.x] = incl;
}

__global__ void scan2_kernel(int* __restrict__ blocksums, int nb) {
  __shared__ int buf[1024];
  int x = threadIdx.x;
  int v = (x < nb) ? blocksums[x] : 0;
  buf[x] = v;
  __syncthreads();
  for (int off = 1; off < 1024; off <<= 1) {
    int t = (x >= off) ? buf[x - off] : 0;
    __syncthreads();
    buf[x] += t;
    __syncthreads();
  }
  if (x < nb) blocksums[x] = buf[x] - v;      // exclusive block offsets
}

__global__ void scan3_kernel(int* __restrict__ excl, const int* __restrict__ blocksums,
                             int* __restrict__ cursor, int N) {
  int i = blockIdx.x * 256 + threadIdx.x;
  if (i < N) {
    int v = excl[i] + blocksums[blockIdx.x];
    excl[i] = v;        // final global exclusive offsets
    cursor[i] = v;      // scatter cursors start at the same place
  }
}

// ---------- Phase C: scatter edge ids into sorted order ----------
__global__ void scatter_kernel(const int* __restrict__ dst, int* __restrict__ cursor,
                               int* __restrict__ order, int E, int N) {
  int e = blockIdx.x * blockDim.x + threadIdx.x;
  if (e < E) {
    int d = dst[e];
    if (d >= 0 && d < N) {
      int pos = atomicAdd(&cursor[d], 1);
      order[pos] = e;
    }
  }
}

// ---------- Phase D: gather-reduce, 8 threads per node ----------
__global__ void gather_kernel(const float4* __restrict__ data,
                              const int* __restrict__ order,
                              const int* __restrict__ offsets,
                              const int* __restrict__ counts,
                              float4* __restrict__ out, int N) {
  int tid = blockIdx.x * blockDim.x + threadIdx.x;
  int n = tid >> 3;
  int q = tid & 7;
  if (n >= N) return;
  int start = offsets[n];
  int cnt = counts[n];
  float4 acc = make_float4(0.f, 0.f, 0.f, 0.f);
  // 2-way unroll: two independent row loads in flight per thread.
  float4 acc2 = make_float4(0.f, 0.f, 0.f, 0.f);
  int i = 0;
  for (; i + 1 < cnt; i += 2) {
    int e0 = order[start + i];
    int e1 = order[start + i + 1];
    float4 v0 = data[(size_t)e0 * 8 + q];
    float4 v1 = data[(size_t)e1 * 8 + q];
    acc.x += v0.x; acc.y += v0.y; acc.z += v0.z; acc.w += v0.w;
    acc2.x += v1.x; acc2.y += v1.y; acc2.z += v1.z; acc2.w += v1.w;
  }
  if (i < cnt) {
    int e0 = order[start + i];
    float4 v0 = data[(size_t)e0 * 8 + q];
    acc.x += v0.x; acc.y += v0.y; acc.z += v0.z; acc.w += v0.w;
  }
  acc.x = (acc.x + acc2.x) * FACTOR;
  acc.y = (acc.y + acc2.y) * FACTOR;
  acc.z = (acc.z + acc2.z) * FACTOR;
  acc.w = (acc.w + acc2.w) * FACTOR;
  out[(size_t)n * 8 + q] = acc;
}

// ---------- Fallback: round-1 atomic scatter (if ws too small) ----------
__global__ void atomic_kernel(const float4* __restrict__ edge_data,
                              const int* __restrict__ edge_dst,
                              float* __restrict__ out, int E, int N) {
  int tid = blockIdx.x * blockDim.x + threadIdx.x;
  int e = tid >> 3;
  int q = tid & 7;
  if (e >= E) return;
  int dst = edge_dst[e];
  if (dst < 0 || dst >= N) return;
  float4 v = edge_data[(size_t)e * 8 + q];
  float* p = out + (size_t)dst * D + q * 4;
  unsafeAtomicAdd(p + 0, v.x * FACTOR);
  unsafeAtomicAdd(p + 1, v.y * FACTOR);
  unsafeAtomicAdd(p + 2, v.z * FACTOR);
  unsafeAtomicAdd(p + 3, v.w * FACTOR);
}

extern "C" void kernel_launch(void* const* d_in, const int* in_sizes, int n_in,
                              void* d_out, int out_size, void* d_ws, size_t ws_size,
                              hipStream_t stream) {
  const float4* edge_data = (const float4*)d_in[0];
  const int* edge_dst = (const int*)d_in[1];

  int E = in_sizes[1];
  int N = out_size / D;

  int nb1 = (N + 255) / 256;     // scan blocks (391 for N=100K)
  size_t need = ((size_t)3 * N + 1024 + E) * sizeof(int);

  if (nb1 > 1024 || ws_size < need) {
    // Fallback: pure atomic scatter.
    float* out = (float*)d_out;
    hipMemsetAsync(d_out, 0, (size_t)out_size * sizeof(float), stream);
    int total = E * 8;
    atomic_kernel<<<(total + 255) / 256, 256, 0, stream>>>(edge_data, edge_dst, out, E, N);
    return;
  }

  int* ws = (int*)d_ws;
  int* counts    = ws;                  // [N]
  int* offsets   = ws + N;              // [N]
  int* cursor    = ws + 2 * N;          // [N]
  int* blocksums = ws + 3 * N;          // [1024]
  int* order     = ws + 3 * N + 1024;   // [E]

  hipMemsetAsync(counts, 0, (size_t)N * sizeof(int), stream);

  count_kernel<<<(E + 255) / 256, 256, 0, stream>>>(edge_dst, counts, E, N);
  scan1_kernel<<<nb1, 256, 0, stream>>>(counts, offsets, blocksums, N);
  scan2_kernel<<<1, 1024, 0, stream>>>(blocksums, nb1);
  scan3_kernel<<<nb1, 256, 0, stream>>>(offsets, blocksums, cursor, N);
  scatter_kernel<<<(E + 255) / 256, 256, 0, stream>>>(edge_dst, cursor, order, E, N);

  int total = N * 8;
  gather_kernel<<<(total + 255) / 256, 256, 0, stream>>>(
      edge_data, order, offsets, counts, (float4*)d_out, N);
}